// Round 14
// baseline (23.805 us; speedup 1.0000x reference)
//
#include <hip/hip_runtime.h>

// Chamfer loss via MFMA, B=16, N=4096, D=3, fp32 in/out. Single dispatch.
// d2[p][q] = ||p||^2 + ||q||^2 - 2 p.q as one 32x32x16 f16 MFMA per tile,
// hi/lo f16 split (error ~1e-3; ||q||^2 added per-column after the min).
// 1024-thread blocks (16 waves = 4 waves/SIMD), 1 block/CU. Each block:
// 512 output cols x ALL 4096 rows -> complete min -> plain stores.
// Rows staged in 4 double-buffered 1024-row LDS chunks (64 KB).
// Inner loop: 4-deep NAMED-REGISTER a-tile prefetch (A0..A3) -- each tile's
// replacement ds_read issues right after its MFMA and is consumed 4 tiles
// later (~100+ cyc), so ~120-cyc LDS latency leaves the critical path.
// (r11/r12 lesson: keep register arrays small & statically indexed.)

typedef _Float16 half8    __attribute__((ext_vector_type(8)));
typedef float    floatx16 __attribute__((ext_vector_type(16)));

#define CH_B 16
#define CH_N 4096
#define CH_BLOCK 1024                  // 16 waves
#define CH_COLS 512                    // output cols per block (32/wave)
#define CH_NCT (CH_N / CH_COLS)        // 8 col-tiles per (dir,b)
#define CH_CHUNK 1024                  // staged rows per chunk
#define CH_NCHUNK (CH_N / CH_CHUNK)    // 4
#define CH_CT (CH_CHUNK / 32)          // 32 row-tiles per chunk
#define CH_NBLK (2 * CH_B * CH_NCT)    // 256 blocks (1 per CU)

__global__ __launch_bounds__(CH_BLOCK, 4) void chamfer_one(
    const float* __restrict__ src, const float* __restrict__ trg,
    float* __restrict__ out_all)
{
    __shared__ half8 sp[2][CH_CT * 64];   // 2 x 32 KB A-fragment buffers

    const int tid  = threadIdx.x;
    const int lane = tid & 63;
    const int wave = tid >> 6;            // 0..15
    const int l31  = lane & 31;
    const int lhi  = lane >> 5;

    const int L   = blockIdx.x;           // 0..255
    const int ct  = L & (CH_NCT - 1);     // col-tile
    const int bz  = L >> 3;               // dir*16 + b
    const int b   = bz & (CH_B - 1);
    const int dir = bz >> 4;

    const float* P  = dir ? trg : src;
    const float* Q  = dir ? src : trg;
    const float* Pb = P + (size_t)b * CH_N * 3;
    const float* Qb = Q + (size_t)b * CH_N * 3;
    float* out = out_all + ((size_t)dir * CH_B + b) * CH_N;

    // ---- B fragment: 32 cols per wave ----
    const int col0 = ct * CH_COLS + wave * 32 + l31;
    float qn, m = __builtin_inff();
    half8 bfrag;
    {
        const float qx = Qb[col0 * 3 + 0], qy = Qb[col0 * 3 + 1], qz = Qb[col0 * 3 + 2];
        qn = qx * qx + qy * qy + qz * qz;
        const _Float16 xh = (_Float16)qx, yh = (_Float16)qy, zh = (_Float16)qz;
        const _Float16 xl = (_Float16)(qx - (float)xh);
        const _Float16 yl = (_Float16)(qy - (float)yh);
        const _Float16 zl = (_Float16)(qz - (float)zh);
        half8 f;
        if (lhi == 0) {      // k = 0..7
            f[0] = (_Float16)1.0f; f[1] = (_Float16)1.0f;
            f[2] = xh; f[3] = yh; f[4] = zh;
            f[5] = xh; f[6] = yh; f[7] = zh;
        } else {             // k = 8..15
            f[0] = xl; f[1] = yl; f[2] = zl;
            f[3] = (_Float16)0.0f; f[4] = (_Float16)0.0f;
            f[5] = (_Float16)0.0f; f[6] = (_Float16)0.0f; f[7] = (_Float16)0.0f;
        }
        bfrag = f;
    }

    // ---- staging: 1 row per thread per chunk (scalar loads) ----
    float pa[3];
    auto loadpts = [&](int c) {
        const float* base = Pb + ((size_t)c * CH_CHUNK + tid) * 3;
        pa[0] = base[0];
        pa[1] = base[1];
        pa[2] = base[2];
    };
    auto writept = [&](int buf) {
        const float ax = -2.0f * pa[0], ay = -2.0f * pa[1], az = -2.0f * pa[2];
        const float pn = pa[0] * pa[0] + pa[1] * pa[1] + pa[2] * pa[2];
        const _Float16 axh = (_Float16)ax, ayh = (_Float16)ay, azh = (_Float16)az;
        const _Float16 axl = (_Float16)(ax - (float)axh);
        const _Float16 ayl = (_Float16)(ay - (float)ayh);
        const _Float16 azl = (_Float16)(az - (float)azh);
        const _Float16 pnh = (_Float16)pn, pnl = (_Float16)(pn - (float)pnh);
        const _Float16 z0 = (_Float16)0.0f;
        const half8 k0 = {pnh, pnl, axh, ayh, azh, axl, ayl, azl};  // k 0..7
        const half8 k1 = {axh, ayh, azh, z0, z0, z0, z0, z0};       // k 8..15
        sp[buf][(tid >> 5) * 64 + (tid & 31)]      = k0;
        sp[buf][(tid >> 5) * 64 + 32 + (tid & 31)] = k1;
    };

    // prologue: stage chunk 0
    loadpts(0);
    writept(0);
    __syncthreads();

    const floatx16 zero = {0.f,0.f,0.f,0.f,0.f,0.f,0.f,0.f,
                           0.f,0.f,0.f,0.f,0.f,0.f,0.f,0.f};
    const int off = wave * 2;   // per-wave tile-phase stagger (0..30)

    // min3-shaped reduction of one MFMA result into m
    auto tree = [&](const floatx16& d) {
        const float u0 = fminf(fminf(d[0],  d[1]),  d[2]);
        const float u1 = fminf(fminf(d[3],  d[4]),  d[5]);
        const float u2 = fminf(fminf(d[6],  d[7]),  d[8]);
        const float u3 = fminf(fminf(d[9],  d[10]), d[11]);
        const float u4 = fminf(fminf(d[12], d[13]), d[14]);
        const float v  = fminf(fminf(u0, u1), u2);
        const float w  = fminf(fminf(u3, u4), d[15]);
        m = fminf(fminf(m, v), w);
    };

    #pragma unroll 1
    for (int c = 0; c < CH_NCHUNK; ++c) {
        const int cur = c & 1;
        const bool more = (c + 1 < CH_NCHUNK);
        if (more) loadpts(c + 1);   // issue early; consumed after compute

        const half8* buf = sp[cur];
        // 4-deep named-register prefetch (indices mod CH_CT via &31)
        half8 A0 = buf[((off + 0) & (CH_CT - 1)) * 64 + lane];
        half8 A1 = buf[((off + 1) & (CH_CT - 1)) * 64 + lane];
        half8 A2 = buf[((off + 2) & (CH_CT - 1)) * 64 + lane];
        half8 A3 = buf[((off + 3) & (CH_CT - 1)) * 64 + lane];

        #pragma unroll 1
        for (int t = 0; t < CH_CT; t += 4) {
            floatx16 d;
            d = __builtin_amdgcn_mfma_f32_32x32x16_f16(A0, bfrag, zero, 0, 0, 0);
            if (t + 4 < CH_CT) A0 = buf[((t + 4 + off) & (CH_CT - 1)) * 64 + lane];
            tree(d);
            d = __builtin_amdgcn_mfma_f32_32x32x16_f16(A1, bfrag, zero, 0, 0, 0);
            if (t + 5 < CH_CT) A1 = buf[((t + 5 + off) & (CH_CT - 1)) * 64 + lane];
            tree(d);
            d = __builtin_amdgcn_mfma_f32_32x32x16_f16(A2, bfrag, zero, 0, 0, 0);
            if (t + 6 < CH_CT) A2 = buf[((t + 6 + off) & (CH_CT - 1)) * 64 + lane];
            tree(d);
            d = __builtin_amdgcn_mfma_f32_32x32x16_f16(A3, bfrag, zero, 0, 0, 0);
            if (t + 7 < CH_CT) A3 = buf[((t + 7 + off) & (CH_CT - 1)) * 64 + lane];
            tree(d);
        }

        if (more) writept(cur ^ 1);   // LDS writes late (load latency hidden)
        __syncthreads();
    }

    // ---- epilogue: add ||q||^2, clamp >=0, fold row-halves, plain store ----
    float v = fmaxf(m + qn, 0.0f);
    v = fminf(v, __shfl_xor(v, 32));
    if (lane < 32) out[col0] = v;
}

extern "C" void kernel_launch(void* const* d_in, const int* in_sizes, int n_in,
                              void* d_out, int out_size, void* d_ws, size_t ws_size,
                              hipStream_t stream) {
    const float* src = (const float*)d_in[0];
    const float* trg = (const float*)d_in[1];
    float* out = (float*)d_out;

    chamfer_one<<<dim3(CH_NBLK), dim3(CH_BLOCK), 0, stream>>>(src, trg, out);
}

// Round 15
// 21.408 us; speedup vs baseline: 1.1119x; 1.1119x over previous
//
#include <hip/hip_runtime.h>

// Chamfer loss via MFMA, B=16, N=4096, D=3, fp32 in/out. Single dispatch.
// d2[p][q] = ||p||^2 + ||q||^2 - 2 p.q as one 32x32x16 f16 MFMA per tile,
// hi/lo f16 split (error ~1e-3; ||q||^2 added per-column after the min).
// 1024-thread blocks (16 waves = 4 waves/SIMD), 1 block/CU. Each block:
// 512 output cols x ALL 4096 rows -> complete min -> plain stores.
// Rows staged in 4 double-buffered 1024-row LDS chunks (64 KB).
// Inner loop: 1-slot SOFTWARE-PIPELINED accumulator (issue MFMA(t+1), then
// min-tree(t)) + 4-deep named-register A prefetch. Max 2 live floatx16,
// all indices static, unconditional main loop + peeled epilogue
// (r11/r12 lesson: conditional/dynamic register state -> scratch spill).

typedef _Float16 half8    __attribute__((ext_vector_type(8)));
typedef float    floatx16 __attribute__((ext_vector_type(16)));

#define CH_B 16
#define CH_N 4096
#define CH_BLOCK 1024                  // 16 waves
#define CH_COLS 512                    // output cols per block (32/wave)
#define CH_NCT (CH_N / CH_COLS)        // 8 col-tiles per (dir,b)
#define CH_CHUNK 1024                  // staged rows per chunk
#define CH_NCHUNK (CH_N / CH_CHUNK)    // 4
#define CH_CT (CH_CHUNK / 32)          // 32 row-tiles per chunk
#define CH_NBLK (2 * CH_B * CH_NCT)    // 256 blocks (1 per CU)

__global__ __launch_bounds__(CH_BLOCK, 4) void chamfer_one(
    const float* __restrict__ src, const float* __restrict__ trg,
    float* __restrict__ out_all)
{
    __shared__ half8 sp[2][CH_CT * 64];   // 2 x 32 KB A-fragment buffers

    const int tid  = threadIdx.x;
    const int lane = tid & 63;
    const int wave = tid >> 6;            // 0..15
    const int l31  = lane & 31;
    const int lhi  = lane >> 5;

    const int L   = blockIdx.x;           // 0..255
    const int ct  = L & (CH_NCT - 1);     // col-tile
    const int bz  = L >> 3;               // dir*16 + b
    const int b   = bz & (CH_B - 1);
    const int dir = bz >> 4;

    const float* P  = dir ? trg : src;
    const float* Q  = dir ? src : trg;
    const float* Pb = P + (size_t)b * CH_N * 3;
    const float* Qb = Q + (size_t)b * CH_N * 3;
    float* out = out_all + ((size_t)dir * CH_B + b) * CH_N;

    // ---- B fragment: 32 cols per wave ----
    const int col0 = ct * CH_COLS + wave * 32 + l31;
    float qn, m = __builtin_inff();
    half8 bfrag;
    {
        const float qx = Qb[col0 * 3 + 0], qy = Qb[col0 * 3 + 1], qz = Qb[col0 * 3 + 2];
        qn = qx * qx + qy * qy + qz * qz;
        const _Float16 xh = (_Float16)qx, yh = (_Float16)qy, zh = (_Float16)qz;
        const _Float16 xl = (_Float16)(qx - (float)xh);
        const _Float16 yl = (_Float16)(qy - (float)yh);
        const _Float16 zl = (_Float16)(qz - (float)zh);
        half8 f;
        if (lhi == 0) {      // k = 0..7
            f[0] = (_Float16)1.0f; f[1] = (_Float16)1.0f;
            f[2] = xh; f[3] = yh; f[4] = zh;
            f[5] = xh; f[6] = yh; f[7] = zh;
        } else {             // k = 8..15
            f[0] = xl; f[1] = yl; f[2] = zl;
            f[3] = (_Float16)0.0f; f[4] = (_Float16)0.0f;
            f[5] = (_Float16)0.0f; f[6] = (_Float16)0.0f; f[7] = (_Float16)0.0f;
        }
        bfrag = f;
    }

    // ---- staging: 1 row per thread per chunk (scalar loads) ----
    float pa[3];
    auto loadpts = [&](int c) {
        const float* base = Pb + ((size_t)c * CH_CHUNK + tid) * 3;
        pa[0] = base[0];
        pa[1] = base[1];
        pa[2] = base[2];
    };
    auto writept = [&](int buf) {
        const float ax = -2.0f * pa[0], ay = -2.0f * pa[1], az = -2.0f * pa[2];
        const float pn = pa[0] * pa[0] + pa[1] * pa[1] + pa[2] * pa[2];
        const _Float16 axh = (_Float16)ax, ayh = (_Float16)ay, azh = (_Float16)az;
        const _Float16 axl = (_Float16)(ax - (float)axh);
        const _Float16 ayl = (_Float16)(ay - (float)ayh);
        const _Float16 azl = (_Float16)(az - (float)azh);
        const _Float16 pnh = (_Float16)pn, pnl = (_Float16)(pn - (float)pnh);
        const _Float16 z0 = (_Float16)0.0f;
        const half8 k0 = {pnh, pnl, axh, ayh, azh, axl, ayl, azl};  // k 0..7
        const half8 k1 = {axh, ayh, azh, z0, z0, z0, z0, z0};       // k 8..15
        sp[buf][(tid >> 5) * 64 + (tid & 31)]      = k0;
        sp[buf][(tid >> 5) * 64 + 32 + (tid & 31)] = k1;
    };

    // prologue: stage chunk 0
    loadpts(0);
    writept(0);
    __syncthreads();

    const floatx16 zero = {0.f,0.f,0.f,0.f,0.f,0.f,0.f,0.f,
                           0.f,0.f,0.f,0.f,0.f,0.f,0.f,0.f};

    // min3-shaped reduction of one MFMA result into m
    auto tree = [&](const floatx16& d) {
        const float u0 = fminf(fminf(d[0],  d[1]),  d[2]);
        const float u1 = fminf(fminf(d[3],  d[4]),  d[5]);
        const float u2 = fminf(fminf(d[6],  d[7]),  d[8]);
        const float u3 = fminf(fminf(d[9],  d[10]), d[11]);
        const float u4 = fminf(fminf(d[12], d[13]), d[14]);
        const float v  = fminf(fminf(u0, u1), u2);
        const float w  = fminf(fminf(u3, u4), d[15]);
        m = fminf(fminf(m, v), w);
    };

    #pragma unroll 1
    for (int c = 0; c < CH_NCHUNK; ++c) {
        const int cur = c & 1;
        const bool more = (c + 1 < CH_NCHUNK);
        if (more) loadpts(c + 1);   // issue early; consumed after compute

        const half8* buf = sp[cur];

        // 4-deep A prefetch + 1-slot d pipeline (max 2 live floatx16)
        half8 A0 = buf[0 * 64 + lane];
        half8 A1 = buf[1 * 64 + lane];
        half8 A2 = buf[2 * 64 + lane];
        half8 A3 = buf[3 * 64 + lane];
        floatx16 d0 = __builtin_amdgcn_mfma_f32_32x32x16_f16(A0, bfrag, zero, 0, 0, 0);

        #pragma unroll 1
        for (int t = 0; t <= CH_CT - 8; t += 4) {   // t = 0..24, tiles 0..27
            floatx16 d1 = __builtin_amdgcn_mfma_f32_32x32x16_f16(A1, bfrag, zero, 0, 0, 0);
            A0 = buf[(t + 4) * 64 + lane];
            tree(d0);
            floatx16 d2 = __builtin_amdgcn_mfma_f32_32x32x16_f16(A2, bfrag, zero, 0, 0, 0);
            A1 = buf[(t + 5) * 64 + lane];
            tree(d1);
            floatx16 d3 = __builtin_amdgcn_mfma_f32_32x32x16_f16(A3, bfrag, zero, 0, 0, 0);
            A2 = buf[(t + 6) * 64 + lane];
            tree(d2);
            d0 = __builtin_amdgcn_mfma_f32_32x32x16_f16(A0, bfrag, zero, 0, 0, 0);
            A3 = buf[(t + 7) * 64 + lane];
            tree(d3);
        }
        // epilogue: tiles CT-4..CT-1 (d0 already holds tile CT-4's result)
        {
            floatx16 e1 = __builtin_amdgcn_mfma_f32_32x32x16_f16(A1, bfrag, zero, 0, 0, 0);
            tree(d0);
            floatx16 e2 = __builtin_amdgcn_mfma_f32_32x32x16_f16(A2, bfrag, zero, 0, 0, 0);
            tree(e1);
            floatx16 e3 = __builtin_amdgcn_mfma_f32_32x32x16_f16(A3, bfrag, zero, 0, 0, 0);
            tree(e2);
            tree(e3);
        }

        if (more) writept(cur ^ 1);   // LDS writes late (load latency hidden)
        __syncthreads();
    }

    // ---- epilogue: add ||q||^2, clamp >=0, fold row-halves, plain store ----
    float v = fmaxf(m + qn, 0.0f);
    v = fminf(v, __shfl_xor(v, 32));
    if (lane < 32) out[col0] = v;
}

extern "C" void kernel_launch(void* const* d_in, const int* in_sizes, int n_in,
                              void* d_out, int out_size, void* d_ws, size_t ws_size,
                              hipStream_t stream) {
    const float* src = (const float*)d_in[0];
    const float* trg = (const float*)d_in[1];
    float* out = (float*)d_out;

    chamfer_one<<<dim3(CH_NBLK), dim3(CH_BLOCK), 0, stream>>>(src, trg, out);
}